// Round 3
// baseline (567.536 us; speedup 1.0000x reference)
//
#include <hip/hip_runtime.h>
#include <math.h>

#define NB 64
#define NT 512
#define ND 768
#define NK 29
#define NCRF 16                    // CRF blocks (4 batches each)
#define L2E 1.4426950408889634f
#define LN2 0.6931471805599453f
#define NEG_BIG -1e30f

typedef __attribute__((ext_vector_type(8))) short short8;
typedef __attribute__((ext_vector_type(4))) float floatx4;

__device__ __forceinline__ short bf16r(float f) {   // round-to-nearest-even
    unsigned u = __float_as_uint(f);
    unsigned r = (u + 0x7FFFu + ((u >> 16) & 1u)) >> 16;
    return (short)r;
}

// ---------------------------------------------------------------------------
// Kernel 0: convert w (29x768 fp32) -> wbf (32x768 bf16, rows 29..31 zero)
// ---------------------------------------------------------------------------
__global__ __launch_bounds__(256) void k_prep(const float* __restrict__ w,
                                              short* __restrict__ wbf)
{
    int i = blockIdx.x * 256 + threadIdx.x;            // 32*768 = 24576
    if (i < 32 * ND) {
        int row = i / ND;
        wbf[i] = (row < NK) ? bf16r(w[i]) : (short)0;
    }
}

// ---------------------------------------------------------------------------
// Kernel 1: emissions via bf16 MFMA (unchanged from R2; bitwise-proven).
// ---------------------------------------------------------------------------
__global__ __launch_bounds__(128) void k_emissions(
    const int* __restrict__ x, const float* __restrict__ emb,
    const short* __restrict__ wbf, const float* __restrict__ bias,
    float* __restrict__ em)
{
    __shared__ float red[2 * 256];                     // wave1 partials
    const int lane = threadIdx.x & 63;
    const int wv = threadIdx.x >> 6;                   // d-half (0/1)
    const int col = lane & 15;                         // m for A, n for B
    const int quad = lane >> 4;                        // k-subrange selector
    const int Mbase = blockIdx.x * 16;
    const int tok = Mbase + col;

    const float* arow = emb + (size_t)x[tok] * ND + wv * 384 + quad * 8;
    const short* brow0 = wbf + (size_t)col * ND + wv * 384 + quad * 8;
    const short* brow1 = brow0 + 16 * ND;

    // issue ALL A loads first: 24 x global_load_dwordx4 in flight
    float4 a[24];
#pragma unroll
    for (int c = 0; c < 12; ++c) {
        a[2 * c]     = *(const float4*)(arow + c * 32);
        a[2 * c + 1] = *(const float4*)(arow + c * 32 + 4);
    }

    floatx4 acc0 = {0.f, 0.f, 0.f, 0.f};
    floatx4 acc1 = {0.f, 0.f, 0.f, 0.f};

    short8 b0 = *(const short8*)(brow0);               // B is L2-hot (45 KB)
    short8 b1 = *(const short8*)(brow1);

#pragma unroll
    for (int c = 0; c < 12; ++c) {
        int c1 = (c + 1 <= 11) ? c + 1 : 11;           // clamped prefetch
        short8 nb0 = *(const short8*)(brow0 + c1 * 32);
        short8 nb1 = *(const short8*)(brow1 + c1 * 32);

        short8 af;
        af[0] = bf16r(a[2 * c].x);     af[1] = bf16r(a[2 * c].y);
        af[2] = bf16r(a[2 * c].z);     af[3] = bf16r(a[2 * c].w);
        af[4] = bf16r(a[2 * c + 1].x); af[5] = bf16r(a[2 * c + 1].y);
        af[6] = bf16r(a[2 * c + 1].z); af[7] = bf16r(a[2 * c + 1].w);

        acc0 = __builtin_amdgcn_mfma_f32_16x16x32_bf16(af, b0, acc0, 0, 0, 0);
        acc1 = __builtin_amdgcn_mfma_f32_16x16x32_bf16(af, b1, acc1, 0, 0, 0);

        b0 = nb0; b1 = nb1;
    }

    // reduce the two d-halves; C/D layout: row = quad*4+reg, col = lane&15
    const int r0 = quad * 4;
    if (wv == 1) {
#pragma unroll
        for (int reg = 0; reg < 4; ++reg) {
            red[(r0 + reg) * 16 + col]       = acc0[reg];
            red[256 + (r0 + reg) * 16 + col] = acc1[reg];
        }
    }
    __syncthreads();
    if (wv == 0) {
        float bs0 = bias[col];
        float bs1 = (col < NK - 16) ? bias[16 + col] : 0.f;
#pragma unroll
        for (int reg = 0; reg < 4; ++reg) {
            int row = r0 + reg;
            float v0 = acc0[reg] + red[row * 16 + col] + bs0;
            em[(size_t)(Mbase + row) * NK + col] = v0;
            if (col < NK - 16) {
                float v1 = acc1[reg] + red[256 + row * 16 + col] + bs1;
                em[(size_t)(Mbase + row) * NK + 16 + col] = v1;
            }
        }
    }
}

// ---------------------------------------------------------------------------
// Kernel 2: scans with MULTI-CHAIN SOFTWARE INTERLEAVE. One wave runs several
// independent batches' serial chains back-to-back in its instruction stream,
// so chain A's LDS-roundtrip/tournament latency hides under chain B's issue
// (single-wave SIMDs were ~70% stall before). Per-chain arithmetic is
// VERBATIM R0 (absmax-0 proven): same LDS sA broadcast, same quad-fma CRF
// sums, same strided keep-left tournament, same renorm probes.
// Blocks 0..15: CRF x4 batches. Blocks 16..47: Viterbi x2 batches.
// CRF no longer stages em in LDS (4 batches won't fit; em is L2-resident and
// read <=2x -- values identical, scheduling-only change).
// ---------------------------------------------------------------------------
__global__ __launch_bounds__(64) void k_scan(
    const float* __restrict__ em, const int* __restrict__ tags,
    const float* __restrict__ st, const float* __restrict__ en,
    const float* __restrict__ tr, float* __restrict__ part,
    float* __restrict__ out)
{
    __shared__ __align__(16) float sAll[4 * 32];       // per-chain state vecs
    __shared__ __align__(16) unsigned char smem[2 * 511 * 32 + 512];
    const int lane = threadIdx.x;
    const int jc = (lane < NK) ? lane : NK - 1;        // R0 lane-clamp

    if (blockIdx.x < NCRF) {
        // ----------------- CRF forward x4 (scaled exp domain) ---------------
        const int bI = blockIdx.x;
        const float* emk[4];
        const int* tgk[4];
#pragma unroll
        for (int k = 0; k < 4; ++k) {
            emk[k] = em + (size_t)(4 * bI + k) * NT * NK;
            tgk[k] = tags + (size_t)(4 * bI + k) * NT;
        }
        float EC[32];
#pragma unroll
        for (int i = 0; i < NK; ++i) EC[i] = __expf(tr[i * NK + jc]);
#pragma unroll
        for (int i = NK; i < 32; ++i) EC[i] = 0.f;

        float anew[4], eemc[4], rawn[4];
        int eshift[4];
#pragma unroll
        for (int k = 0; k < 4; ++k) {
            anew[k] = __expf(st[jc] + emk[k][jc]);
            if (lane < 32) sAll[32 * k + lane] = (lane < NK) ? anew[k] : 0.f;
            eshift[k] = 5 * (NT - 1);
            eemc[k] = exp2f(fmaf(emk[k][NK + jc], L2E, -5.0f));
            rawn[k] = emk[k][2 * NK + jc];
        }

        for (int t = 1; t < NT; ++t) {
#pragma unroll
            for (int k = 0; k < 4; ++k) {
                const float4* sA4 = (const float4*)(sAll + 32 * k);
                float4 A[8];
#pragma unroll
                for (int ii = 0; ii < 8; ++ii) A[ii] = sA4[ii];  // broadcast
                float p0 = 0.f, p1 = 0.f, p2 = 0.f, p3 = 0.f;
#pragma unroll
                for (int ii = 0; ii < 8; ++ii) {                 // pads: +0
                    p0 = fmaf(A[ii].x, EC[4 * ii + 0], p0);
                    p1 = fmaf(A[ii].y, EC[4 * ii + 1], p1);
                    p2 = fmaf(A[ii].z, EC[4 * ii + 2], p2);
                    p3 = fmaf(A[ii].w, EC[4 * ii + 3], p3);
                }
                anew[k] = ((p0 + p1) + (p2 + p3)) * eemc[k];
                // refill (off critical chain)
                eemc[k] = exp2f(fmaf(rawn[k], L2E, -5.0f));
                int tn = t + 2; tn = tn < NT ? tn : NT - 1;
                rawn[k] = emk[k][tn * NK + jc];
            }
            if ((t & 15) == 0) {       // exact pow2 renorm via lane-0 probe
#pragma unroll
                for (int k = 0; k < 4; ++k) {
                    unsigned mb = (unsigned)__builtin_amdgcn_readfirstlane(
                                      __float_as_int(anew[k]));
                    int ex = (int)((mb >> 23) & 255u) - 127;
                    anew[k] *= __int_as_float((unsigned)(127 - ex) << 23);
                    eshift[k] += ex;
                }
            }
#pragma unroll
            for (int k = 0; k < 4; ++k)
                if (lane < 32) sAll[32 * k + lane] = (lane < NK) ? anew[k] : 0.f;
        }

        // num: 4 chains interleaved, fully unrolled so gathers pipeline
        float pp[4] = {0.f, 0.f, 0.f, 0.f};
#pragma unroll
        for (int it = 0; it < 8; ++it) {
            int t = lane + 64 * it;
#pragma unroll
            for (int k = 0; k < 4; ++k) {
                int tt = tgk[k][t];
                pp[k] += emk[k][t * NK + tt];
                if (t == 0) pp[k] += st[tt];
                else        pp[k] += tr[tgk[k][t - 1] * NK + tt];
                if (t == NT - 1) pp[k] += en[tt];
            }
        }
#pragma unroll
        for (int k = 0; k < 4; ++k) {
            float val = (lane < NK) ? anew[k] * __expf(en[jc]) : 0.f;
#pragma unroll
            for (int s = 32; s; s >>= 1) val += __shfl_xor(val, s);
            float logZ = logf(val) + (float)eshift[k] * LN2;
            float p = pp[k];
#pragma unroll
            for (int s = 32; s; s >>= 1) p += __shfl_xor(p, s);
            if (lane == 0) part[4 * bI + k] = logZ - p;
        }
    } else {
        // ----------------- Viterbi x2 + parallel backtrace ------------------
        const int b0 = 2 * (blockIdx.x - NCRF);
        const float* emA = em + (size_t)b0 * NT * NK;
        const float* emB = emA + NT * NK;
        unsigned char* sbpA = smem;                    // [511][32]
        unsigned char* sbpB = smem + 511 * 32;         // [511][32]
        unsigned char* smap = smem + 2 * 511 * 32;     // [16][32] (reused)
        float* sA_A = sAll;
        float* sA_B = sAll + 32;
        const float4* sA_A4 = (const float4*)sA_A;
        const float4* sA_B4 = (const float4*)sA_B;

        float Tc[32];                                  // shared by both chains
#pragma unroll
        for (int i = 0; i < NK; ++i) Tc[i] = tr[i * NK + jc];
#pragma unroll
        for (int i = NK; i < 32; ++i) Tc[i] = 0.f;

        float scA = (lane < NK) ? (st[jc] + emA[jc]) : NEG_BIG;
        float scB = (lane < NK) ? (st[jc] + emB[jc]) : NEG_BIG;
        if (lane < 32) {
            sA_A[lane] = (lane < NK) ? scA : NEG_BIG;
            sA_B[lane] = (lane < NK) ? scB : NEG_BIG;
        }

        float eA0 = emA[1 * NK + jc], eA1 = emA[2 * NK + jc];
        float eA2 = emA[3 * NK + jc], eA3 = emA[4 * NK + jc];
        float eB0 = emB[1 * NK + jc], eB1 = emB[2 * NK + jc];
        float eB2 = emB[3 * NK + jc], eB3 = emB[4 * NK + jc];

        auto vstep2 = [&](int t, float emtA, float emtB) {
            float4 qA[8], qB[8];                       // both issued early
#pragma unroll
            for (int ii = 0; ii < 8; ++ii) qA[ii] = sA_A4[ii];
#pragma unroll
            for (int ii = 0; ii < 8; ++ii) qB[ii] = sA_B4[ii];
            {   // chain A (verbatim R0 eval)
                float v[32]; int id[32];
#pragma unroll
                for (int ii = 0; ii < 8; ++ii) {
                    v[4 * ii + 0] = qA[ii].x + Tc[4 * ii + 0];
                    v[4 * ii + 1] = qA[ii].y + Tc[4 * ii + 1];
                    v[4 * ii + 2] = qA[ii].z + Tc[4 * ii + 2];
                    v[4 * ii + 3] = qA[ii].w + Tc[4 * ii + 3];
                }
#pragma unroll
                for (int i = 0; i < 32; ++i) id[i] = i;
#pragma unroll
                for (int w2 = 16; w2 >= 1; w2 >>= 1)
#pragma unroll
                    for (int i = 0; i < 16; ++i) if (i < w2) {
                        bool g = v[i + w2] > v[i];
                        v[i] = g ? v[i + w2] : v[i];
                        id[i] = g ? id[i + w2] : id[i];
                    }
                if (lane < 32) sbpA[(t - 1) * 32 + lane] = (unsigned char)id[0];
                scA = (lane < NK) ? (v[0] + emtA) : NEG_BIG;
                if (lane < 32) sA_A[lane] = (lane < NK) ? scA : NEG_BIG;
            }
            {   // chain B (independent -> fills A's stall cycles)
                float v[32]; int id[32];
#pragma unroll
                for (int ii = 0; ii < 8; ++ii) {
                    v[4 * ii + 0] = qB[ii].x + Tc[4 * ii + 0];
                    v[4 * ii + 1] = qB[ii].y + Tc[4 * ii + 1];
                    v[4 * ii + 2] = qB[ii].z + Tc[4 * ii + 2];
                    v[4 * ii + 3] = qB[ii].w + Tc[4 * ii + 3];
                }
#pragma unroll
                for (int i = 0; i < 32; ++i) id[i] = i;
#pragma unroll
                for (int w2 = 16; w2 >= 1; w2 >>= 1)
#pragma unroll
                    for (int i = 0; i < 16; ++i) if (i < w2) {
                        bool g = v[i + w2] > v[i];
                        v[i] = g ? v[i + w2] : v[i];
                        id[i] = g ? id[i + w2] : id[i];
                    }
                if (lane < 32) sbpB[(t - 1) * 32 + lane] = (unsigned char)id[0];
                scB = (lane < NK) ? (v[0] + emtB) : NEG_BIG;
                if (lane < 32) sA_B[lane] = (lane < NK) ? scB : NEG_BIG;
            }
        };

        int t = 1;
        for (; t + 3 < NT; t += 4) {
            vstep2(t + 0, eA0, eB0);
            { int tn = t + 4; tn = tn < NT ? tn : NT - 1;
              eA0 = emA[tn * NK + jc]; eB0 = emB[tn * NK + jc]; }
            vstep2(t + 1, eA1, eB1);
            { int tn = t + 5; tn = tn < NT ? tn : NT - 1;
              eA1 = emA[tn * NK + jc]; eB1 = emB[tn * NK + jc]; }
            vstep2(t + 2, eA2, eB2);
            { int tn = t + 6; tn = tn < NT ? tn : NT - 1;
              eA2 = emA[tn * NK + jc]; eB2 = emB[tn * NK + jc]; }
            vstep2(t + 3, eA3, eB3);
            { int tn = t + 7; tn = tn < NT ? tn : NT - 1;
              eA3 = emA[tn * NK + jc]; eB3 = emB[tn * NK + jc]; }
        }
        vstep2(509, eA0, eB0); vstep2(510, eA1, eB1); vstep2(511, eA2, eB2);

        // finals (verbatim R0 per chain)
        float vfA = (lane < NK) ? (scA + en[jc]) : NEG_BIG;
        float MA = vfA;
#pragma unroll
        for (int s = 32; s; s >>= 1) MA = fmaxf(MA, __shfl_xor(MA, s));
        unsigned long long mkA = __ballot((lane < NK) && vfA == MA);
        int lastA = (int)__builtin_ctzll(mkA);

        float vfB = (lane < NK) ? (scB + en[jc]) : NEG_BIG;
        float MB = vfB;
#pragma unroll
        for (int s = 32; s; s >>= 1) MB = fmaxf(MB, __shfl_xor(MB, s));
        unsigned long long mkB = __ballot((lane < NK) && vfB == MB);
        int lastB = (int)__builtin_ctzll(mkB);

        const int c = lane & 31;
        const int h = lane >> 5;
#pragma unroll
        for (int chain = 0; chain < 2; ++chain) {
            const unsigned char* sbp = chain ? sbpB : sbpA;
            int last = chain ? lastB : lastA;
            float* op = out + 1 + (size_t)(b0 + chain) * NT;

            int cur8[8];
#pragma unroll
            for (int rep = 0; rep < 8; ++rep) cur8[rep] = c;
            for (int off = 0; off < 32; ++off) {
#pragma unroll
                for (int rep = 0; rep < 8; ++rep) {
                    int s = 2 * rep + h;
                    int hi = (s == 15) ? 511 : 32 * s + 32;
                    int r = hi - 1 - off;
                    if (r >= 32 * s) cur8[rep] = sbp[r * 32 + cur8[rep]];
                }
            }
#pragma unroll
            for (int rep = 0; rep < 8; ++rep)
                smap[(2 * rep + h) * 32 + c] = (unsigned char)cur8[rep];

            int myhi = 0, cur = last;
            for (int s = 15; s >= 0; --s) {
                if (lane == s) myhi = cur;
                cur = smap[s * 32 + cur];
            }
            if (lane == 16) op[NT - 1] = (float)last;
            if (lane < 16) {
                int s = lane;
                int hi = (s == 15) ? 511 : 32 * s + 32;
                int cc = myhi;
                for (int r = hi - 1; r >= 32 * s; --r) {
                    cc = sbp[r * 32 + cc];
                    op[r] = (float)cc;
                }
            }
        }
    }
}

// ---------------------------------------------------------------------------
// Kernel 3: nll = sum_b (logZ_b - num_b)
// ---------------------------------------------------------------------------
__global__ __launch_bounds__(64) void k_finish(const float* __restrict__ part,
                                               float* __restrict__ out)
{
    float v = part[threadIdx.x];
#pragma unroll
    for (int s = 32; s; s >>= 1) v += __shfl_xor(v, s);
    if (threadIdx.x == 0) out[0] = v;
}

extern "C" void kernel_launch(void* const* d_in, const int* in_sizes, int n_in,
                              void* d_out, int out_size, void* d_ws, size_t ws_size,
                              hipStream_t stream) {
    const int*   x    = (const int*)d_in[0];
    const int*   tags = (const int*)d_in[1];
    const float* emb  = (const float*)d_in[2];
    const float* w    = (const float*)d_in[3];
    const float* bias = (const float*)d_in[4];
    const float* st   = (const float*)d_in[5];
    const float* en   = (const float*)d_in[6];
    const float* tr   = (const float*)d_in[7];
    float* out = (float*)d_out;

    short* wbf  = (short*)d_ws;                              // 48 KB
    float* part = (float*)((char*)d_ws + 49152);             // 256 B
    float* em   = (float*)((char*)d_ws + 65536);             // 3.8 MB

    k_prep<<<96, 256, 0, stream>>>(w, wbf);
    k_emissions<<<2048, 128, 0, stream>>>(x, emb, wbf, bias, em);
    k_scan<<<NCRF + NB / 2, 64, 0, stream>>>(em, tags, st, en, tr, part, out);
    k_finish<<<1, 64, 0, stream>>>(part, out);
}

// Round 4
// 509.989 us; speedup vs baseline: 1.1128x; 1.1128x over previous
//
#include <hip/hip_runtime.h>
#include <math.h>

#define NB 64
#define NT 512
#define ND 768
#define NK 29
#define L2E 1.4426950408889634f
#define LN2 0.6931471805599453f
#define NEG_BIG -1e30f

typedef __attribute__((ext_vector_type(8))) short short8;
typedef __attribute__((ext_vector_type(4))) float floatx4;

__device__ __forceinline__ short bf16r(float f) {   // round-to-nearest-even
    unsigned u = __float_as_uint(f);
    unsigned r = (u + 0x7FFFu + ((u >> 16) & 1u)) >> 16;
    return (short)r;
}

// ---------------------------------------------------------------------------
// Kernel 0: convert w (29x768 fp32) -> wbf (32x768 bf16, rows 29..31 zero)
// ---------------------------------------------------------------------------
__global__ __launch_bounds__(256) void k_prep(const float* __restrict__ w,
                                              short* __restrict__ wbf)
{
    int i = blockIdx.x * 256 + threadIdx.x;            // 32*768 = 24576
    if (i < 32 * ND) {
        int row = i / ND;
        wbf[i] = (row < NK) ? bf16r(w[i]) : (short)0;
    }
}

// ---------------------------------------------------------------------------
// Kernel 1: emissions via bf16 MFMA (bitwise-proven across R0-R3; unchanged).
// ---------------------------------------------------------------------------
__global__ __launch_bounds__(128) void k_emissions(
    const int* __restrict__ x, const float* __restrict__ emb,
    const short* __restrict__ wbf, const float* __restrict__ bias,
    float* __restrict__ em)
{
    __shared__ float red[2 * 256];                     // wave1 partials
    const int lane = threadIdx.x & 63;
    const int wv = threadIdx.x >> 6;                   // d-half (0/1)
    const int col = lane & 15;                         // m for A, n for B
    const int quad = lane >> 4;                        // k-subrange selector
    const int Mbase = blockIdx.x * 16;
    const int tok = Mbase + col;

    const float* arow = emb + (size_t)x[tok] * ND + wv * 384 + quad * 8;
    const short* brow0 = wbf + (size_t)col * ND + wv * 384 + quad * 8;
    const short* brow1 = brow0 + 16 * ND;

    // issue ALL A loads first: 24 x global_load_dwordx4 in flight
    float4 a[24];
#pragma unroll
    for (int c = 0; c < 12; ++c) {
        a[2 * c]     = *(const float4*)(arow + c * 32);
        a[2 * c + 1] = *(const float4*)(arow + c * 32 + 4);
    }

    floatx4 acc0 = {0.f, 0.f, 0.f, 0.f};
    floatx4 acc1 = {0.f, 0.f, 0.f, 0.f};

    short8 b0 = *(const short8*)(brow0);               // B is L2-hot (45 KB)
    short8 b1 = *(const short8*)(brow1);

#pragma unroll
    for (int c = 0; c < 12; ++c) {
        int c1 = (c + 1 <= 11) ? c + 1 : 11;           // clamped prefetch
        short8 nb0 = *(const short8*)(brow0 + c1 * 32);
        short8 nb1 = *(const short8*)(brow1 + c1 * 32);

        short8 af;
        af[0] = bf16r(a[2 * c].x);     af[1] = bf16r(a[2 * c].y);
        af[2] = bf16r(a[2 * c].z);     af[3] = bf16r(a[2 * c].w);
        af[4] = bf16r(a[2 * c + 1].x); af[5] = bf16r(a[2 * c + 1].y);
        af[6] = bf16r(a[2 * c + 1].z); af[7] = bf16r(a[2 * c + 1].w);

        acc0 = __builtin_amdgcn_mfma_f32_16x16x32_bf16(af, b0, acc0, 0, 0, 0);
        acc1 = __builtin_amdgcn_mfma_f32_16x16x32_bf16(af, b1, acc1, 0, 0, 0);

        b0 = nb0; b1 = nb1;
    }

    // reduce the two d-halves; C/D layout: row = quad*4+reg, col = lane&15
    const int r0 = quad * 4;
    if (wv == 1) {
#pragma unroll
        for (int reg = 0; reg < 4; ++reg) {
            red[(r0 + reg) * 16 + col]       = acc0[reg];
            red[256 + (r0 + reg) * 16 + col] = acc1[reg];
        }
    }
    __syncthreads();
    if (wv == 0) {
        float bs0 = bias[col];
        float bs1 = (col < NK - 16) ? bias[16 + col] : 0.f;
#pragma unroll
        for (int reg = 0; reg < 4; ++reg) {
            int row = r0 + reg;
            float v0 = acc0[reg] + red[row * 16 + col] + bs0;
            em[(size_t)(Mbase + row) * NK + col] = v0;
            if (col < NK - 16) {
                float v1 = acc1[reg] + red[256 + row * 16 + col] + bs1;
                em[(size_t)(Mbase + row) * NK + 16 + col] = v1;
            }
        }
    }
}

// ---------------------------------------------------------------------------
// Kernel 2: serial scans, ISSUE-OPTIMIZED. Blocks 0..63: CRF (verbatim R0).
// Blocks 64..127: Viterbi forward VALUES-ONLY — no argmax-id tracking on the
// serial wave (that was ~125 of ~199 instrs/step). Max reduced via fmaxf
// triple-tree: max is EXACT, so the value is bitwise = R0's tournament value.
// State rows are streamed to global; k_bp recomputes backpointers in parallel.
// ---------------------------------------------------------------------------
__global__ __launch_bounds__(64) void k_scan(
    const float* __restrict__ em, const int* __restrict__ tags,
    const float* __restrict__ st, const float* __restrict__ en,
    const float* __restrict__ tr, float* __restrict__ part,
    float* __restrict__ states)
{
    __shared__ __align__(16) float sA[32];
    __shared__ __align__(16) unsigned char smem[NT * NK * 4];
    const float4* sA4 = (const float4*)sA;
    const int lane = threadIdx.x;
    const int jc = (lane < NK) ? lane : NK - 1;

    if (blockIdx.x < NB) {
        // ----------------- CRF forward (verbatim R0) -----------------------
        const int b = blockIdx.x;
        float* emS = (float*)smem;                     // [512][29]
        {
            const float4* src = (const float4*)(em + (size_t)b * NT * NK);
            float4* dst = (float4*)emS;
            for (int i = lane; i < NT * NK / 4; i += 64) dst[i] = src[i];
        }
        float EC[32];
#pragma unroll
        for (int i = 0; i < NK; ++i) EC[i] = __expf(tr[i * NK + jc]);
#pragma unroll
        for (int i = NK; i < 32; ++i) EC[i] = 0.f;

        float a0v = __expf(st[jc] + emS[jc]);
        if (lane < 32) sA[lane] = (lane < NK) ? a0v : 0.f;

        int eshift = 5 * (NT - 1);
        float eemc = exp2f(fmaf(emS[NK + jc], L2E, -5.0f));
        float rawn = emS[2 * NK + jc];
        float anew = a0v;

        for (int t = 1; t < NT; ++t) {
            float4 A[8];
#pragma unroll
            for (int ii = 0; ii < 8; ++ii) A[ii] = sA4[ii];   // broadcast reads
            float p0 = 0.f, p1 = 0.f, p2 = 0.f, p3 = 0.f;
#pragma unroll
            for (int ii = 0; ii < 8; ++ii) {                  // pads: +0 exact
                p0 = fmaf(A[ii].x, EC[4 * ii + 0], p0);
                p1 = fmaf(A[ii].y, EC[4 * ii + 1], p1);
                p2 = fmaf(A[ii].z, EC[4 * ii + 2], p2);
                p3 = fmaf(A[ii].w, EC[4 * ii + 3], p3);
            }
            anew = ((p0 + p1) + (p2 + p3)) * eemc;
            // refill (off critical chain)
            eemc = exp2f(fmaf(rawn, L2E, -5.0f));
            int tn = t + 2; tn = tn < NT ? tn : NT - 1;
            rawn = emS[tn * NK + jc];

            if ((t & 15) == 0) {       // exact pow2 renorm via lane-0 probe
                unsigned mb = (unsigned)__builtin_amdgcn_readfirstlane(
                                  __float_as_int(anew));
                int ex = (int)((mb >> 23) & 255u) - 127;
                anew *= __int_as_float((unsigned)(127 - ex) << 23);
                eshift += ex;
            }
            if (lane < 32) sA[lane] = (lane < NK) ? anew : 0.f;
        }
        float val = (lane < NK) ? anew * __expf(en[jc]) : 0.f;
#pragma unroll
        for (int s = 32; s; s >>= 1) val += __shfl_xor(val, s);
        float logZ = logf(val) + (float)eshift * LN2;
        const int* tg = tags + b * NT;
        float p = 0.f;
        for (int t = lane; t < NT; t += 64) {
            int tt = tg[t];
            p += emS[t * NK + tt];
            if (t == 0) p += st[tt];
            else        p += tr[tg[t - 1] * NK + tt];
            if (t == NT - 1) p += en[tt];
        }
#pragma unroll
        for (int s = 32; s; s >>= 1) p += __shfl_xor(p, s);
        if (lane == 0) part[b] = logZ - p;
    } else {
        // ------------- Viterbi forward, values-only (no id tracking) -------
        const int b = blockIdx.x - NB;
        const float* emb_b = em + (size_t)b * NT * NK;
        float* stt = states + (size_t)b * NT * 32;     // padded rows

        float Tc[32];
#pragma unroll
        for (int i = 0; i < NK; ++i) Tc[i] = tr[i * NK + jc];
#pragma unroll
        for (int i = NK; i < 32; ++i) Tc[i] = 0.f;

        float sc = (lane < NK) ? (st[jc] + emb_b[jc]) : NEG_BIG;
        if (lane < 32) { sA[lane] = sc; stt[lane] = sc; }  // lanes 29..31: NEG_BIG

        float e0 = emb_b[1 * NK + jc];
        float e1 = emb_b[2 * NK + jc];
        float e2 = emb_b[3 * NK + jc];
        float e3 = emb_b[4 * NK + jc];

        auto vstep = [&](int t, float emt) {
            float4 q[8];
#pragma unroll
            for (int ii = 0; ii < 8; ++ii) q[ii] = sA4[ii];   // broadcast reads
            float v[32];
#pragma unroll
            for (int ii = 0; ii < 8; ++ii) {
                v[4 * ii + 0] = q[ii].x + Tc[4 * ii + 0];
                v[4 * ii + 1] = q[ii].y + Tc[4 * ii + 1];
                v[4 * ii + 2] = q[ii].z + Tc[4 * ii + 2];
                v[4 * ii + 3] = q[ii].w + Tc[4 * ii + 3];
            }
            // exact max via triple-tree (fmax is exact: bitwise == tournament
            // value; triples coax v_max3_f32)
            float w0 = fmaxf(fmaxf(v[0], v[1]), v[2]);
            float w1 = fmaxf(fmaxf(v[3], v[4]), v[5]);
            float w2 = fmaxf(fmaxf(v[6], v[7]), v[8]);
            float w3 = fmaxf(fmaxf(v[9], v[10]), v[11]);
            float w4 = fmaxf(fmaxf(v[12], v[13]), v[14]);
            float w5 = fmaxf(fmaxf(v[15], v[16]), v[17]);
            float w6 = fmaxf(fmaxf(v[18], v[19]), v[20]);
            float w7 = fmaxf(fmaxf(v[21], v[22]), v[23]);
            float w8 = fmaxf(fmaxf(v[24], v[25]), v[26]);
            float w9 = fmaxf(fmaxf(v[27], v[28]), v[29]);
            float wa = fmaxf(v[30], v[31]);
            float u0 = fmaxf(fmaxf(w0, w1), w2);
            float u1 = fmaxf(fmaxf(w3, w4), w5);
            float u2 = fmaxf(fmaxf(w6, w7), w8);
            float u3 = fmaxf(w9, wa);
            float m  = fmaxf(fmaxf(fmaxf(u0, u1), u2), u3);

            sc = (lane < NK) ? (m + emt) : NEG_BIG;
            if (lane < 32) { sA[lane] = sc; stt[t * 32 + lane] = sc; }
        };

        int t = 1;
        for (; t + 3 < NT; t += 4) {
            vstep(t + 0, e0); { int tn = t + 4; tn = tn < NT ? tn : NT - 1; e0 = emb_b[tn * NK + jc]; }
            vstep(t + 1, e1); { int tn = t + 5; tn = tn < NT ? tn : NT - 1; e1 = emb_b[tn * NK + jc]; }
            vstep(t + 2, e2); { int tn = t + 6; tn = tn < NT ? tn : NT - 1; e2 = emb_b[tn * NK + jc]; }
            vstep(t + 3, e3); { int tn = t + 7; tn = tn < NT ? tn : NT - 1; e3 = emb_b[tn * NK + jc]; }
        }
        vstep(509, e0); vstep(510, e1); vstep(511, e2);
        // finals + backtrace moved to k_bp
    }
}

// ---------------------------------------------------------------------------
// Kernel 2b: backpointer recompute (massively parallel) + backtrace.
// bp[t][c] = R0-VERBATIM strided keep-left tournament on bitwise-identical
// inputs (stored state rows + tr) => bp bitwise == R0's sbp => path bitwise.
// 64 blocks x 512 threads; states staged to LDS in two 256-row halves.
// ---------------------------------------------------------------------------
__global__ __launch_bounds__(512) void k_bp(
    const float* __restrict__ states, const float* __restrict__ en,
    const float* __restrict__ tr, float* __restrict__ out)
{
    __shared__ __align__(16) float stt[256 * 32];          // 32 KB
    __shared__ unsigned char sbp[511 * 32];                // 16 KB
    __shared__ unsigned char smap[16 * 32];
    const int b = blockIdx.x;
    const float* S = states + (size_t)b * NT * 32;
    const int tid = threadIdx.x;
    const int c = tid & 31;
    const int jc = (c < NK) ? c : NK - 1;
    const int g = tid >> 5;                                // 0..15 (row group)

    float Tc[32];
#pragma unroll
    for (int i = 0; i < NK; ++i) Tc[i] = tr[i * NK + jc];
#pragma unroll
    for (int i = NK; i < 32; ++i) Tc[i] = 0.f;

    for (int half = 0; half < 2; ++half) {
        __syncthreads();
        {   // stage state rows [256*half, 256*half+255] (coalesced float4)
            const float4* src = (const float4*)(S + half * 256 * 32);
            float4* dst = (float4*)stt;
#pragma unroll
            for (int i = 0; i < 4; ++i) dst[tid + 512 * i] = src[tid + 512 * i];
        }
        __syncthreads();
        // bp[t] for t in [256h+1, 256h+256] ∩ [1,511]; row (t-1-256h) is
        // uniform across each 32-lane group => ds_read broadcast.
#pragma unroll 1
        for (int k = 0; k < 16; ++k) {
            int t = 256 * half + 1 + g + 16 * k;
            if (t < NT) {
                const float4* row = (const float4*)(stt + (t - 1 - 256 * half) * 32);
                float v[32]; int id[32];
#pragma unroll
                for (int ii = 0; ii < 8; ++ii) {
                    float4 q = row[ii];
                    v[4 * ii + 0] = q.x + Tc[4 * ii + 0];
                    v[4 * ii + 1] = q.y + Tc[4 * ii + 1];
                    v[4 * ii + 2] = q.z + Tc[4 * ii + 2];
                    v[4 * ii + 3] = q.w + Tc[4 * ii + 3];
                }
#pragma unroll
                for (int i = 0; i < 32; ++i) id[i] = i;
                // R0 strided keep-left tournament (verbatim tie semantics)
#pragma unroll
                for (int w2 = 16; w2 >= 1; w2 >>= 1)
#pragma unroll
                    for (int i = 0; i < 16; ++i) if (i < w2) {
                        bool gg = v[i + w2] > v[i];
                        v[i] = gg ? v[i + w2] : v[i];
                        id[i] = gg ? id[i + w2] : id[i];
                    }
                sbp[(t - 1) * 32 + c] = (unsigned char)id[0];
            }
        }
    }
    __syncthreads();

    if (tid < 64) {    // wave 0: finals + segmented backtrace (verbatim R0)
        const int lane = tid;
        float vfin = (lane < NK) ? (stt[255 * 32 + lane] + en[jc]) : NEG_BIG;
        float M = vfin;
#pragma unroll
        for (int s = 32; s; s >>= 1) M = fmaxf(M, __shfl_xor(M, s));
        unsigned long long mk = __ballot((lane < NK) && vfin == M);
        int last = (int)__builtin_ctzll(mk);

        const int cl = lane & 31;
        const int h = lane >> 5;
        int cur8[8];
#pragma unroll
        for (int rep = 0; rep < 8; ++rep) cur8[rep] = cl;
        for (int off = 0; off < 32; ++off) {
#pragma unroll
            for (int rep = 0; rep < 8; ++rep) {
                int s = 2 * rep + h;
                int hi = (s == 15) ? 511 : 32 * s + 32;
                int r = hi - 1 - off;
                if (r >= 32 * s) cur8[rep] = sbp[r * 32 + cur8[rep]];
            }
        }
#pragma unroll
        for (int rep = 0; rep < 8; ++rep)
            smap[(2 * rep + h) * 32 + cl] = (unsigned char)cur8[rep];

        int myhi = 0, cur = last;
        for (int s = 15; s >= 0; --s) {
            if (lane == s) myhi = cur;
            cur = smap[s * 32 + cur];
        }
        float* op = out + 1 + (size_t)b * NT;
        if (lane == 16) op[NT - 1] = (float)last;
        if (lane < 16) {
            int s = lane;
            int hi = (s == 15) ? 511 : 32 * s + 32;
            int cc = myhi;
            for (int r = hi - 1; r >= 32 * s; --r) {
                cc = sbp[r * 32 + cc];
                op[r] = (float)cc;
            }
        }
    }
}

// ---------------------------------------------------------------------------
// Kernel 3: nll = sum_b (logZ_b - num_b)
// ---------------------------------------------------------------------------
__global__ __launch_bounds__(64) void k_finish(const float* __restrict__ part,
                                               float* __restrict__ out)
{
    float v = part[threadIdx.x];
#pragma unroll
    for (int s = 32; s; s >>= 1) v += __shfl_xor(v, s);
    if (threadIdx.x == 0) out[0] = v;
}

extern "C" void kernel_launch(void* const* d_in, const int* in_sizes, int n_in,
                              void* d_out, int out_size, void* d_ws, size_t ws_size,
                              hipStream_t stream) {
    const int*   x    = (const int*)d_in[0];
    const int*   tags = (const int*)d_in[1];
    const float* emb  = (const float*)d_in[2];
    const float* w    = (const float*)d_in[3];
    const float* bias = (const float*)d_in[4];
    const float* st   = (const float*)d_in[5];
    const float* en   = (const float*)d_in[6];
    const float* tr   = (const float*)d_in[7];
    float* out = (float*)d_out;

    short* wbf    = (short*)d_ws;                            // 48 KB
    float* part   = (float*)((char*)d_ws + 49152);           // 256 B
    float* em     = (float*)((char*)d_ws + 65536);           // 3.80 MB
    float* states = (float*)((char*)d_ws + 3932160);         // 4.19 MB (ws ~8.2 MB)

    k_prep<<<96, 256, 0, stream>>>(w, wbf);
    k_emissions<<<2048, 128, 0, stream>>>(x, emb, wbf, bias, em);
    k_scan<<<2 * NB, 64, 0, stream>>>(em, tags, st, en, tr, part, states);
    k_bp<<<NB, 512, 0, stream>>>(states, en, tr, out);
    k_finish<<<1, 64, 0, stream>>>(part, out);
}

// Round 5
// 399.427 us; speedup vs baseline: 1.4209x; 1.2768x over previous
//
#include <hip/hip_runtime.h>
#include <math.h>

#define NB 64
#define NT 512
#define ND 768
#define NK 29
#define L2E 1.4426950408889634f
#define LN2 0.6931471805599453f
#define NEG_BIG -1e30f

typedef __attribute__((ext_vector_type(8))) short short8;
typedef __attribute__((ext_vector_type(4))) float floatx4;

__device__ __forceinline__ short bf16r(float f) {   // round-to-nearest-even
    unsigned u = __float_as_uint(f);
    unsigned r = (u + 0x7FFFu + ((u >> 16) & 1u)) >> 16;
    return (short)r;
}

// ---------------------------------------------------------------------------
// Kernel 0: convert w (29x768 fp32) -> wbf (32x768 bf16, rows 29..31 zero)
// ---------------------------------------------------------------------------
__global__ __launch_bounds__(256) void k_prep(const float* __restrict__ w,
                                              short* __restrict__ wbf)
{
    int i = blockIdx.x * 256 + threadIdx.x;            // 32*768 = 24576
    if (i < 32 * ND) {
        int row = i / ND;
        wbf[i] = (row < NK) ? bf16r(w[i]) : (short)0;
    }
}

// ---------------------------------------------------------------------------
// Kernel 1: emissions via bf16 MFMA (bitwise-proven across R0-R4; unchanged).
// ---------------------------------------------------------------------------
__global__ __launch_bounds__(128) void k_emissions(
    const int* __restrict__ x, const float* __restrict__ emb,
    const short* __restrict__ wbf, const float* __restrict__ bias,
    float* __restrict__ em)
{
    __shared__ float red[2 * 256];                     // wave1 partials
    const int lane = threadIdx.x & 63;
    const int wv = threadIdx.x >> 6;                   // d-half (0/1)
    const int col = lane & 15;                         // m for A, n for B
    const int quad = lane >> 4;                        // k-subrange selector
    const int Mbase = blockIdx.x * 16;
    const int tok = Mbase + col;

    const float* arow = emb + (size_t)x[tok] * ND + wv * 384 + quad * 8;
    const short* brow0 = wbf + (size_t)col * ND + wv * 384 + quad * 8;
    const short* brow1 = brow0 + 16 * ND;

    // issue ALL A loads first: 24 x global_load_dwordx4 in flight
    float4 a[24];
#pragma unroll
    for (int c = 0; c < 12; ++c) {
        a[2 * c]     = *(const float4*)(arow + c * 32);
        a[2 * c + 1] = *(const float4*)(arow + c * 32 + 4);
    }

    floatx4 acc0 = {0.f, 0.f, 0.f, 0.f};
    floatx4 acc1 = {0.f, 0.f, 0.f, 0.f};

    short8 b0 = *(const short8*)(brow0);               // B is L2-hot (45 KB)
    short8 b1 = *(const short8*)(brow1);

#pragma unroll
    for (int c = 0; c < 12; ++c) {
        int c1 = (c + 1 <= 11) ? c + 1 : 11;           // clamped prefetch
        short8 nb0 = *(const short8*)(brow0 + c1 * 32);
        short8 nb1 = *(const short8*)(brow1 + c1 * 32);

        short8 af;
        af[0] = bf16r(a[2 * c].x);     af[1] = bf16r(a[2 * c].y);
        af[2] = bf16r(a[2 * c].z);     af[3] = bf16r(a[2 * c].w);
        af[4] = bf16r(a[2 * c + 1].x); af[5] = bf16r(a[2 * c + 1].y);
        af[6] = bf16r(a[2 * c + 1].z); af[7] = bf16r(a[2 * c + 1].w);

        acc0 = __builtin_amdgcn_mfma_f32_16x16x32_bf16(af, b0, acc0, 0, 0, 0);
        acc1 = __builtin_amdgcn_mfma_f32_16x16x32_bf16(af, b1, acc1, 0, 0, 0);

        b0 = nb0; b1 = nb1;
    }

    // reduce the two d-halves; C/D layout: row = quad*4+reg, col = lane&15
    const int r0 = quad * 4;
    if (wv == 1) {
#pragma unroll
        for (int reg = 0; reg < 4; ++reg) {
            red[(r0 + reg) * 16 + col]       = acc0[reg];
            red[256 + (r0 + reg) * 16 + col] = acc1[reg];
        }
    }
    __syncthreads();
    if (wv == 0) {
        float bs0 = bias[col];
        float bs1 = (col < NK - 16) ? bias[16 + col] : 0.f;
#pragma unroll
        for (int reg = 0; reg < 4; ++reg) {
            int row = r0 + reg;
            float v0 = acc0[reg] + red[row * 16 + col] + bs0;
            em[(size_t)(Mbase + row) * NK + col] = v0;
            if (col < NK - 16) {
                float v1 = acc1[reg] + red[256 + row * 16 + col] + bs1;
                em[(size_t)(Mbase + row) * NK + 16 + col] = v1;
            }
        }
    }
}

// ---------------------------------------------------------------------------
// Kernel 2: serial scans. Blocks 0..63: CRF (verbatim R0). Blocks 64..127:
// Viterbi forward VALUES-ONLY (fmax triple-tree; max is exact => value
// bitwise = R0's tournament). State rows streamed to global for k_bp.
// ---------------------------------------------------------------------------
__global__ __launch_bounds__(64) void k_scan(
    const float* __restrict__ em, const int* __restrict__ tags,
    const float* __restrict__ st, const float* __restrict__ en,
    const float* __restrict__ tr, float* __restrict__ part,
    float* __restrict__ states)
{
    __shared__ __align__(16) float sA[32];
    __shared__ __align__(16) unsigned char smem[NT * NK * 4];
    const float4* sA4 = (const float4*)sA;
    const int lane = threadIdx.x;
    const int jc = (lane < NK) ? lane : NK - 1;

    if (blockIdx.x < NB) {
        // ----------------- CRF forward (verbatim R0) -----------------------
        const int b = blockIdx.x;
        float* emS = (float*)smem;                     // [512][29]
        {
            const float4* src = (const float4*)(em + (size_t)b * NT * NK);
            float4* dst = (float4*)emS;
            for (int i = lane; i < NT * NK / 4; i += 64) dst[i] = src[i];
        }
        float EC[32];
#pragma unroll
        for (int i = 0; i < NK; ++i) EC[i] = __expf(tr[i * NK + jc]);
#pragma unroll
        for (int i = NK; i < 32; ++i) EC[i] = 0.f;

        float a0v = __expf(st[jc] + emS[jc]);
        if (lane < 32) sA[lane] = (lane < NK) ? a0v : 0.f;

        int eshift = 5 * (NT - 1);
        float eemc = exp2f(fmaf(emS[NK + jc], L2E, -5.0f));
        float rawn = emS[2 * NK + jc];
        float anew = a0v;

        for (int t = 1; t < NT; ++t) {
            float4 A[8];
#pragma unroll
            for (int ii = 0; ii < 8; ++ii) A[ii] = sA4[ii];   // broadcast reads
            float p0 = 0.f, p1 = 0.f, p2 = 0.f, p3 = 0.f;
#pragma unroll
            for (int ii = 0; ii < 8; ++ii) {                  // pads: +0 exact
                p0 = fmaf(A[ii].x, EC[4 * ii + 0], p0);
                p1 = fmaf(A[ii].y, EC[4 * ii + 1], p1);
                p2 = fmaf(A[ii].z, EC[4 * ii + 2], p2);
                p3 = fmaf(A[ii].w, EC[4 * ii + 3], p3);
            }
            anew = ((p0 + p1) + (p2 + p3)) * eemc;
            // refill (off critical chain)
            eemc = exp2f(fmaf(rawn, L2E, -5.0f));
            int tn = t + 2; tn = tn < NT ? tn : NT - 1;
            rawn = emS[tn * NK + jc];

            if ((t & 15) == 0) {       // exact pow2 renorm via lane-0 probe
                unsigned mb = (unsigned)__builtin_amdgcn_readfirstlane(
                                  __float_as_int(anew));
                int ex = (int)((mb >> 23) & 255u) - 127;
                anew *= __int_as_float((unsigned)(127 - ex) << 23);
                eshift += ex;
            }
            if (lane < 32) sA[lane] = (lane < NK) ? anew : 0.f;
        }
        float val = (lane < NK) ? anew * __expf(en[jc]) : 0.f;
#pragma unroll
        for (int s = 32; s; s >>= 1) val += __shfl_xor(val, s);
        float logZ = logf(val) + (float)eshift * LN2;
        const int* tg = tags + b * NT;
        float p = 0.f;
        for (int t = lane; t < NT; t += 64) {
            int tt = tg[t];
            p += emS[t * NK + tt];
            if (t == 0) p += st[tt];
            else        p += tr[tg[t - 1] * NK + tt];
            if (t == NT - 1) p += en[tt];
        }
#pragma unroll
        for (int s = 32; s; s >>= 1) p += __shfl_xor(p, s);
        if (lane == 0) part[b] = logZ - p;
    } else {
        // ------------- Viterbi forward, values-only (no id tracking) -------
        const int b = blockIdx.x - NB;
        const float* emb_b = em + (size_t)b * NT * NK;
        float* stt = states + (size_t)b * NT * 32;     // padded rows

        float Tc[32];
#pragma unroll
        for (int i = 0; i < NK; ++i) Tc[i] = tr[i * NK + jc];
#pragma unroll
        for (int i = NK; i < 32; ++i) Tc[i] = 0.f;

        float sc = (lane < NK) ? (st[jc] + emb_b[jc]) : NEG_BIG;
        if (lane < 32) { sA[lane] = sc; stt[lane] = sc; }  // lanes 29..31: NEG_BIG

        float e0 = emb_b[1 * NK + jc];
        float e1 = emb_b[2 * NK + jc];
        float e2 = emb_b[3 * NK + jc];
        float e3 = emb_b[4 * NK + jc];

        auto vstep = [&](int t, float emt) {
            float4 q[8];
#pragma unroll
            for (int ii = 0; ii < 8; ++ii) q[ii] = sA4[ii];   // broadcast reads
            float v[32];
#pragma unroll
            for (int ii = 0; ii < 8; ++ii) {
                v[4 * ii + 0] = q[ii].x + Tc[4 * ii + 0];
                v[4 * ii + 1] = q[ii].y + Tc[4 * ii + 1];
                v[4 * ii + 2] = q[ii].z + Tc[4 * ii + 2];
                v[4 * ii + 3] = q[ii].w + Tc[4 * ii + 3];
            }
            // exact max via triple-tree (bitwise == tournament value)
            float w0 = fmaxf(fmaxf(v[0], v[1]), v[2]);
            float w1 = fmaxf(fmaxf(v[3], v[4]), v[5]);
            float w2 = fmaxf(fmaxf(v[6], v[7]), v[8]);
            float w3 = fmaxf(fmaxf(v[9], v[10]), v[11]);
            float w4 = fmaxf(fmaxf(v[12], v[13]), v[14]);
            float w5 = fmaxf(fmaxf(v[15], v[16]), v[17]);
            float w6 = fmaxf(fmaxf(v[18], v[19]), v[20]);
            float w7 = fmaxf(fmaxf(v[21], v[22]), v[23]);
            float w8 = fmaxf(fmaxf(v[24], v[25]), v[26]);
            float w9 = fmaxf(fmaxf(v[27], v[28]), v[29]);
            float wa = fmaxf(v[30], v[31]);
            float u0 = fmaxf(fmaxf(w0, w1), w2);
            float u1 = fmaxf(fmaxf(w3, w4), w5);
            float u2 = fmaxf(fmaxf(w6, w7), w8);
            float u3 = fmaxf(w9, wa);
            float m  = fmaxf(fmaxf(fmaxf(u0, u1), u2), u3);

            sc = (lane < NK) ? (m + emt) : NEG_BIG;
            if (lane < 32) { sA[lane] = sc; stt[t * 32 + lane] = sc; }
        };

        int t = 1;
        for (; t + 3 < NT; t += 4) {
            vstep(t + 0, e0); { int tn = t + 4; tn = tn < NT ? tn : NT - 1; e0 = emb_b[tn * NK + jc]; }
            vstep(t + 1, e1); { int tn = t + 5; tn = tn < NT ? tn : NT - 1; e1 = emb_b[tn * NK + jc]; }
            vstep(t + 2, e2); { int tn = t + 6; tn = tn < NT ? tn : NT - 1; e2 = emb_b[tn * NK + jc]; }
            vstep(t + 3, e3); { int tn = t + 7; tn = tn < NT ? tn : NT - 1; e3 = emb_b[tn * NK + jc]; }
        }
        vstep(509, e0); vstep(510, e1); vstep(511, e2);
        // finals + backtrace moved to k_bp/k_trace
    }
}

// ---------------------------------------------------------------------------
// Kernel 2b: backpointer recompute, massively parallel & REGISTER-RESIDENT.
// 256 blocks x 256 thr, launch_bounds(256,1) so regalloc can hold Tc/v/id
// (R4's 512-thr shape spilled them: VGPR=44, 232us). 4 blocks per batch;
// each stages a 128-row state slice (16KB LDS) and computes 128 bp rows with
// the R0-VERBATIM strided keep-left tournament on bitwise-identical inputs
// => bp bitwise == R0's sbp. bp written to global (aliases dead em buffer).
// ---------------------------------------------------------------------------
__global__ __launch_bounds__(256, 1) void k_bp(
    const float* __restrict__ states, const float* __restrict__ tr,
    unsigned char* __restrict__ bpg)
{
    __shared__ __align__(16) float stt[128 * 32];          // 16 KB
    const int b = blockIdx.x >> 2;
    const int seg = blockIdx.x & 3;
    const int base = seg * 128;                            // state rows staged
    const float* S = states + (size_t)b * NT * 32;
    const int tid = threadIdx.x;
    const int c = tid & 31;
    const int jc = (c < NK) ? c : NK - 1;
    const int g = tid >> 5;                                // 0..7 (row group)

    float Tc[32];
#pragma unroll
    for (int i = 0; i < NK; ++i) Tc[i] = tr[i * NK + jc];
#pragma unroll
    for (int i = NK; i < 32; ++i) Tc[i] = 0.f;

    {   // stage state rows [base, base+127] (coalesced float4)
        const float4* src = (const float4*)(S + base * 32);
        float4* dst = (float4*)stt;
#pragma unroll
        for (int i = 0; i < 4; ++i) dst[tid + 256 * i] = src[tid + 256 * i];
    }
    __syncthreads();

    unsigned char* bpb = bpg + (size_t)b * 511 * 32;
#pragma unroll 1
    for (int k = 0; k < 16; ++k) {
        int t = base + 1 + g + 8 * k;                      // bp row t-1
        if (t < NT) {
            const float4* row = (const float4*)(stt + (t - 1 - base) * 32);
            float v[32]; int id[32];
#pragma unroll
            for (int ii = 0; ii < 8; ++ii) {
                float4 q = row[ii];                        // LDS broadcast
                v[4 * ii + 0] = q.x + Tc[4 * ii + 0];
                v[4 * ii + 1] = q.y + Tc[4 * ii + 1];
                v[4 * ii + 2] = q.z + Tc[4 * ii + 2];
                v[4 * ii + 3] = q.w + Tc[4 * ii + 3];
            }
#pragma unroll
            for (int i = 0; i < 32; ++i) id[i] = i;
            // R0 strided keep-left tournament (verbatim tie semantics)
#pragma unroll
            for (int w2 = 16; w2 >= 1; w2 >>= 1)
#pragma unroll
                for (int i = 0; i < 16; ++i) if (i < w2) {
                    bool gg = v[i + w2] > v[i];
                    v[i] = gg ? v[i + w2] : v[i];
                    id[i] = gg ? id[i + w2] : id[i];
                }
            bpb[(t - 1) * 32 + c] = (unsigned char)id[0];
        }
    }
}

// ---------------------------------------------------------------------------
// Kernel 2c: finals + segmented backtrace (verbatim R0). 64 blocks x 1 wave.
// Stages the batch's 16KB bp into LDS, then exact R0 logic.
// ---------------------------------------------------------------------------
__global__ __launch_bounds__(64) void k_trace(
    const unsigned char* __restrict__ bpg, const float* __restrict__ states,
    const float* __restrict__ en, float* __restrict__ out)
{
    __shared__ __align__(16) unsigned char sbp[511 * 32];  // 16 KB
    __shared__ unsigned char smap[16 * 32];
    const int b = blockIdx.x;
    const int lane = threadIdx.x;
    const int jc = (lane < NK) ? lane : NK - 1;

    {   // stage bp (16352 B = 1022 uint4), coalesced
        const uint4* src = (const uint4*)(bpg + (size_t)b * 511 * 32);
        uint4* dst = (uint4*)sbp;
        for (int i = lane; i < 1022; i += 64) dst[i] = src[i];
    }
    __syncthreads();

    const float* fin = states + (size_t)b * NT * 32 + 511 * 32;
    int li = (lane < 32) ? lane : 0;
    float sv = fin[li];
    float vfin = (lane < NK) ? (sv + en[jc]) : NEG_BIG;
    float M = vfin;
#pragma unroll
    for (int s = 32; s; s >>= 1) M = fmaxf(M, __shfl_xor(M, s));
    unsigned long long mk = __ballot((lane < NK) && vfin == M);
    int last = (int)__builtin_ctzll(mk);

    const int cl = lane & 31;
    const int h = lane >> 5;
    int cur8[8];
#pragma unroll
    for (int rep = 0; rep < 8; ++rep) cur8[rep] = cl;
    for (int off = 0; off < 32; ++off) {
#pragma unroll
        for (int rep = 0; rep < 8; ++rep) {
            int s = 2 * rep + h;
            int hi = (s == 15) ? 511 : 32 * s + 32;
            int r = hi - 1 - off;
            if (r >= 32 * s) cur8[rep] = sbp[r * 32 + cur8[rep]];
        }
    }
#pragma unroll
    for (int rep = 0; rep < 8; ++rep)
        smap[(2 * rep + h) * 32 + cl] = (unsigned char)cur8[rep];

    int myhi = 0, cur = last;
    for (int s = 15; s >= 0; --s) {
        if (lane == s) myhi = cur;
        cur = smap[s * 32 + cur];
    }
    float* op = out + 1 + (size_t)b * NT;
    if (lane == 16) op[NT - 1] = (float)last;
    if (lane < 16) {
        int s = lane;
        int hi = (s == 15) ? 511 : 32 * s + 32;
        int cc = myhi;
        for (int r = hi - 1; r >= 32 * s; --r) {
            cc = sbp[r * 32 + cc];
            op[r] = (float)cc;
        }
    }
}

// ---------------------------------------------------------------------------
// Kernel 3: nll = sum_b (logZ_b - num_b)
// ---------------------------------------------------------------------------
__global__ __launch_bounds__(64) void k_finish(const float* __restrict__ part,
                                               float* __restrict__ out)
{
    float v = part[threadIdx.x];
#pragma unroll
    for (int s = 32; s; s >>= 1) v += __shfl_xor(v, s);
    if (threadIdx.x == 0) out[0] = v;
}

extern "C" void kernel_launch(void* const* d_in, const int* in_sizes, int n_in,
                              void* d_out, int out_size, void* d_ws, size_t ws_size,
                              hipStream_t stream) {
    const int*   x    = (const int*)d_in[0];
    const int*   tags = (const int*)d_in[1];
    const float* emb  = (const float*)d_in[2];
    const float* w    = (const float*)d_in[3];
    const float* bias = (const float*)d_in[4];
    const float* st   = (const float*)d_in[5];
    const float* en   = (const float*)d_in[6];
    const float* tr   = (const float*)d_in[7];
    float* out = (float*)d_out;

    short* wbf    = (short*)d_ws;                            // 48 KB
    float* part   = (float*)((char*)d_ws + 49152);           // 256 B
    float* em     = (float*)((char*)d_ws + 65536);           // 3.80 MB
    float* states = (float*)((char*)d_ws + 3932160);         // 4.19 MB (ws ~8.2 MB)
    // bp aliases em: em is dead after k_scan completes (stream-ordered)
    unsigned char* bp = (unsigned char*)((char*)d_ws + 65536);

    k_prep<<<96, 256, 0, stream>>>(w, wbf);
    k_emissions<<<2048, 128, 0, stream>>>(x, emb, wbf, bias, em);
    k_scan<<<2 * NB, 64, 0, stream>>>(em, tags, st, en, tr, part, states);
    k_bp<<<4 * NB, 256, 0, stream>>>(states, tr, bp);
    k_trace<<<NB, 64, 0, stream>>>(bp, states, en, out);
    k_finish<<<1, 64, 0, stream>>>(part, out);
}